// Round 1
// baseline (517.927 us; speedup 1.0000x reference)
//
#include <hip/hip_runtime.h>
#include <math.h>

#define B_ 16
#define T_ 2048
#define D_ 256
#define W_ 128
#define M_ (B_*T_)   // 32768

// ---------------------------------------------------------------------------
// K1: fused QKV projection GEMM.  C = x @ {Wq,Wk,Wv}; epilogue writes
// q (raw), ek = exp(k), ekv = exp(k)*v.  64x64 tile, 256 threads, 4x4/thread.
// ---------------------------------------------------------------------------
__global__ __launch_bounds__(256) void aft_qkv_gemm(
    const float* __restrict__ x,
    const float* __restrict__ Wq, const float* __restrict__ Wk,
    const float* __restrict__ Wv,
    float* __restrict__ q, float* __restrict__ ek, float* __restrict__ ekv)
{
    __shared__ float As[16][64];    // [k][row]
    __shared__ float Bqs[16][68];   // [k][col], pad 68 keeps 16B row alignment
    __shared__ float Bks[16][68];
    __shared__ float Bvs[16][68];

    const int tid  = threadIdx.x;
    const int row0 = blockIdx.x * 64;
    const int col0 = blockIdx.y * 64;
    const int tx = tid & 15;   // col group
    const int ty = tid >> 4;   // row group

    float accq[4][4] = {{0.f}}, acck[4][4] = {{0.f}}, accv[4][4] = {{0.f}};

    const int arow = tid >> 2;         // 0..63
    const int akq  = (tid & 3) << 2;   // 0,4,8,12
    const int bk   = tid >> 4;         // 0..15
    const int bn   = (tid & 15) << 2;  // 0..60

    for (int k0 = 0; k0 < D_; k0 += 16) {
        const float4 av = *(const float4*)&x[(size_t)(row0 + arow) * D_ + k0 + akq];
        As[akq + 0][arow] = av.x;
        As[akq + 1][arow] = av.y;
        As[akq + 2][arow] = av.z;
        As[akq + 3][arow] = av.w;
        *(float4*)&Bqs[bk][bn] = *(const float4*)&Wq[(size_t)(k0 + bk) * D_ + col0 + bn];
        *(float4*)&Bks[bk][bn] = *(const float4*)&Wk[(size_t)(k0 + bk) * D_ + col0 + bn];
        *(float4*)&Bvs[bk][bn] = *(const float4*)&Wv[(size_t)(k0 + bk) * D_ + col0 + bn];
        __syncthreads();
        #pragma unroll
        for (int kk = 0; kk < 16; ++kk) {
            float4 a4 = *(const float4*)&As[kk][ty << 2];
            float4 q4 = *(const float4*)&Bqs[kk][tx << 2];
            float4 k4 = *(const float4*)&Bks[kk][tx << 2];
            float4 v4 = *(const float4*)&Bvs[kk][tx << 2];
            float a[4]  = {a4.x, a4.y, a4.z, a4.w};
            float bq[4] = {q4.x, q4.y, q4.z, q4.w};
            float bb[4] = {k4.x, k4.y, k4.z, k4.w};
            float bv[4] = {v4.x, v4.y, v4.z, v4.w};
            #pragma unroll
            for (int i = 0; i < 4; ++i)
                #pragma unroll
                for (int j = 0; j < 4; ++j) {
                    accq[i][j] += a[i] * bq[j];
                    acck[i][j] += a[i] * bb[j];
                    accv[i][j] += a[i] * bv[j];
                }
        }
        __syncthreads();
    }

    #pragma unroll
    for (int i = 0; i < 4; ++i) {
        size_t row = (size_t)row0 + (ty << 2) + i;
        size_t off = row * D_ + col0 + (tx << 2);
        float4 qo, eo, vo;
        qo.x = accq[i][0]; qo.y = accq[i][1]; qo.z = accq[i][2]; qo.w = accq[i][3];
        float e0 = expf(acck[i][0]), e1 = expf(acck[i][1]);
        float e2 = expf(acck[i][2]), e3 = expf(acck[i][3]);
        eo.x = e0; eo.y = e1; eo.z = e2; eo.w = e3;
        vo.x = e0 * accv[i][0]; vo.y = e1 * accv[i][1];
        vo.z = e2 * accv[i][2]; vo.w = e3 * accv[i][3];
        *(float4*)&q[off]   = qo;
        *(float4*)&ek[off]  = eo;
        *(float4*)&ekv[off] = vo;
    }
}

// ---------------------------------------------------------------------------
// K2: global sums over t:  Sk[b,d] = sum_t ek[b,t,d],  Sv likewise.
// Chunked over t with atomic accumulation (Sk/Sv zeroed by memset).
// ---------------------------------------------------------------------------
__global__ __launch_bounds__(256) void aft_sums(
    const float* __restrict__ ek, const float* __restrict__ ekv,
    float* __restrict__ Sk, float* __restrict__ Sv)
{
    const int idx = blockIdx.x * 256 + threadIdx.x;  // 0..B*D-1
    const int b = idx >> 8;                          // /D_
    const int d = idx & (D_ - 1);
    const int t0 = blockIdx.y * (T_ / 16);
    float sk = 0.f, sv = 0.f;
    size_t base = ((size_t)b * T_ + t0) * D_ + d;
    for (int t = 0; t < T_ / 16; ++t) {
        sk += ek[base + (size_t)t * D_];
        sv += ekv[base + (size_t)t * D_];
    }
    atomicAdd(&Sk[idx], sk);
    atomicAdd(&Sv[idx], sv);
}

// ---------------------------------------------------------------------------
// K3: band coefficients EW[t][j] = exp(w_bias[t, t-127+j]) - 1, j in [0,255),
// zero outside band / sequence.  Computed once, reused by all 16 batches.
// ---------------------------------------------------------------------------
__global__ __launch_bounds__(256) void aft_ew(
    const float* __restrict__ wb, float* __restrict__ EW)
{
    const int t = blockIdx.x;
    const int j = threadIdx.x;
    const int s = t - (W_ - 1) + j;
    float v = 0.f;
    if (j < 2 * W_ - 1 && s >= 0 && s < T_)
        v = expf(wb[(size_t)t * T_ + s]) - 1.0f;
    EW[(size_t)t * 256 + j] = v;
}

// ---------------------------------------------------------------------------
// K4: banded num/den + fused epilogue y = sigmoid(q) * num/den.
// Block = (16 t) x (128 d) of one batch; s staged through LDS in chunks of 16.
// ---------------------------------------------------------------------------
__global__ __launch_bounds__(256) void aft_band(
    const float* __restrict__ ek, const float* __restrict__ ekv,
    const float* __restrict__ EW,
    const float* __restrict__ Sk, const float* __restrict__ Sv,
    const float* __restrict__ q, float* __restrict__ y)
{
    __shared__ float eks[16][132];   // pad 132: 16B-aligned rows
    __shared__ float ekvs[16][132];
    __shared__ float ews[16][17];

    const int tid = threadIdx.x;
    const int b   = blockIdx.z;
    const int t0  = blockIdx.x * 16;
    const int d0  = blockIdx.y * 128;
    const int tx  = tid & 31;   // d group (4 floats each)
    const int tyg = tid >> 5;   // 0..7 -> t pair

    float4 accn[2], accd[2];
    accn[0] = make_float4(0.f, 0.f, 0.f, 0.f); accn[1] = accn[0];
    accd[0] = accn[0];                          accd[1] = accn[0];

    const int s_start = t0 - (W_ - 1);

    for (int c = 0; c < 17; ++c) {
        const int s_base = s_start + c * 16;
        // stage ek/ekv chunk: 16 s x 128 d
        #pragma unroll
        for (int r = 0; r < 2; ++r) {
            int e  = r * 256 + tid;     // 0..511
            int sl = e >> 5;            // 0..15
            int dg = (e & 31) << 2;     // 0..124
            int s  = s_base + sl;
            float4 a = make_float4(0.f, 0.f, 0.f, 0.f);
            float4 v = a;
            if (s >= 0 && s < T_) {
                size_t off = (((size_t)b * T_ + s) * D_ + d0 + dg);
                a = *(const float4*)&ek[off];
                v = *(const float4*)&ekv[off];
            }
            *(float4*)&eks[sl][dg]  = a;
            *(float4*)&ekvs[sl][dg] = v;
        }
        // stage band coefs: 16 t x 16 s
        {
            int tl = tid >> 4, sl = tid & 15;
            int s  = s_base + sl;
            int j  = s - (t0 + tl) + (W_ - 1);
            float wv = 0.f;
            if (j >= 0 && j < 2 * W_ - 1 && s >= 0 && s < T_)
                wv = EW[(size_t)(t0 + tl) * 256 + j];
            ews[tl][sl] = wv;
        }
        __syncthreads();
        #pragma unroll
        for (int sl = 0; sl < 16; ++sl) {
            float4 ke = *(const float4*)&eks[sl][tx << 2];
            float4 kv = *(const float4*)&ekvs[sl][tx << 2];
            #pragma unroll
            for (int u = 0; u < 2; ++u) {
                float w = ews[tyg * 2 + u][sl];
                accn[u].x += w * kv.x; accn[u].y += w * kv.y;
                accn[u].z += w * kv.z; accn[u].w += w * kv.w;
                accd[u].x += w * ke.x; accd[u].y += w * ke.y;
                accd[u].z += w * ke.z; accd[u].w += w * ke.w;
            }
        }
        __syncthreads();
    }

    const int d = d0 + (tx << 2);
    const float4 skv = *(const float4*)&Sk[b * D_ + d];
    const float4 svv = *(const float4*)&Sv[b * D_ + d];
    #pragma unroll
    for (int u = 0; u < 2; ++u) {
        int t = t0 + tyg * 2 + u;
        size_t off = (((size_t)b * T_ + t) * D_ + d);
        float4 qv = *(const float4*)&q[off];
        float4 o;
        float n0 = svv.x + accn[u].x, dn0 = skv.x + accd[u].x;
        float n1 = svv.y + accn[u].y, dn1 = skv.y + accd[u].y;
        float n2 = svv.z + accn[u].z, dn2 = skv.z + accd[u].z;
        float n3 = svv.w + accn[u].w, dn3 = skv.w + accd[u].w;
        o.x = (1.f / (1.f + expf(-qv.x))) * n0 / dn0;
        o.y = (1.f / (1.f + expf(-qv.y))) * n1 / dn1;
        o.z = (1.f / (1.f + expf(-qv.z))) * n2 / dn2;
        o.w = (1.f / (1.f + expf(-qv.w))) * n3 / dn3;
        *(float4*)&y[off] = o;
    }
}

// ---------------------------------------------------------------------------
// K5: output projection GEMM  out = y @ Wo  (same structure as K1, single B).
// ---------------------------------------------------------------------------
__global__ __launch_bounds__(256) void aft_out_gemm(
    const float* __restrict__ A, const float* __restrict__ Bw,
    float* __restrict__ C)
{
    __shared__ float As[16][64];
    __shared__ float Bs[16][68];

    const int tid  = threadIdx.x;
    const int row0 = blockIdx.x * 64;
    const int col0 = blockIdx.y * 64;
    const int tx = tid & 15;
    const int ty = tid >> 4;

    float acc[4][4] = {{0.f}};

    const int arow = tid >> 2;
    const int akq  = (tid & 3) << 2;
    const int bk   = tid >> 4;
    const int bn   = (tid & 15) << 2;

    for (int k0 = 0; k0 < D_; k0 += 16) {
        const float4 av = *(const float4*)&A[(size_t)(row0 + arow) * D_ + k0 + akq];
        As[akq + 0][arow] = av.x;
        As[akq + 1][arow] = av.y;
        As[akq + 2][arow] = av.z;
        As[akq + 3][arow] = av.w;
        *(float4*)&Bs[bk][bn] = *(const float4*)&Bw[(size_t)(k0 + bk) * D_ + col0 + bn];
        __syncthreads();
        #pragma unroll
        for (int kk = 0; kk < 16; ++kk) {
            float4 a4 = *(const float4*)&As[kk][ty << 2];
            float4 b4 = *(const float4*)&Bs[kk][tx << 2];
            float a[4] = {a4.x, a4.y, a4.z, a4.w};
            float b[4] = {b4.x, b4.y, b4.z, b4.w};
            #pragma unroll
            for (int i = 0; i < 4; ++i)
                #pragma unroll
                for (int j = 0; j < 4; ++j)
                    acc[i][j] += a[i] * b[j];
        }
        __syncthreads();
    }

    #pragma unroll
    for (int i = 0; i < 4; ++i) {
        size_t row = (size_t)row0 + (ty << 2) + i;
        size_t off = row * D_ + col0 + (tx << 2);
        float4 o;
        o.x = acc[i][0]; o.y = acc[i][1]; o.z = acc[i][2]; o.w = acc[i][3];
        *(float4*)&C[off] = o;
    }
}

extern "C" void kernel_launch(void* const* d_in, const int* in_sizes, int n_in,
                              void* d_out, int out_size, void* d_ws, size_t ws_size,
                              hipStream_t stream)
{
    const float* x  = (const float*)d_in[0];
    const float* Wq = (const float*)d_in[1];
    const float* Wk = (const float*)d_in[2];
    const float* Wv = (const float*)d_in[3];
    const float* Wo = (const float*)d_in[4];
    const float* wb = (const float*)d_in[5];
    // window (d_in[6]) is the constant 128, baked in as W_.

    float* ws = (float*)d_ws;
    const size_t N = (size_t)B_ * T_ * D_;   // 8,388,608
    float* q   = ws;
    float* ek  = ws + N;
    float* ekv = ws + 2 * N;
    float* y   = ws + 3 * N;
    float* EW  = ws + 4 * N;                 // T_ * 256 floats
    float* Sk  = EW + (size_t)T_ * 256;      // B_*D_ floats
    float* Sv  = Sk + B_ * D_;               // B_*D_ floats

    hipMemsetAsync(Sk, 0, 2 * B_ * D_ * sizeof(float), stream);

    aft_qkv_gemm<<<dim3(M_ / 64, D_ / 64), 256, 0, stream>>>(x, Wq, Wk, Wv, q, ek, ekv);
    aft_ew<<<dim3(T_), 256, 0, stream>>>(wb, EW);
    aft_sums<<<dim3((B_ * D_) / 256, 16), 256, 0, stream>>>(ek, ekv, Sk, Sv);
    aft_band<<<dim3(T_ / 16, D_ / 128, B_), 256, 0, stream>>>(ek, ekv, EW, Sk, Sv, q, y);
    aft_out_gemm<<<dim3(M_ / 64, D_ / 64), 256, 0, stream>>>(y, Wo, (float*)d_out);
}

// Round 2
// 466.448 us; speedup vs baseline: 1.1104x; 1.1104x over previous
//
#include <hip/hip_runtime.h>
#include <math.h>

#define B_ 16
#define T_ 2048
#define D_ 256
#define W_ 128
#define M_ (B_*T_)   // 32768

// ---------------------------------------------------------------------------
// K1: fused QKV projection GEMM. 128x64 tile, 256 threads, 8x4 per thread x3.
// Epilogue: q (raw), ek = exp(k), ekv = exp(k)*v.
// ---------------------------------------------------------------------------
__global__ __launch_bounds__(256) void aft_qkv_gemm(
    const float* __restrict__ x,
    const float* __restrict__ Wq, const float* __restrict__ Wk,
    const float* __restrict__ Wv,
    float* __restrict__ q, float* __restrict__ ek, float* __restrict__ ekv)
{
    __shared__ float As[16][132];   // [k][row], 128 rows
    __shared__ float Bqs[16][68];   // [k][col], 64 cols
    __shared__ float Bks[16][68];
    __shared__ float Bvs[16][68];

    const int tid  = threadIdx.x;
    const int row0 = blockIdx.x * 128;
    const int col0 = blockIdx.y * 64;
    const int tx = tid & 15;   // col group (4 cols)
    const int ty = tid >> 4;   // row group (8 rows)

    float accq[8][4] = {{0.f}}, acck[8][4] = {{0.f}}, accv[8][4] = {{0.f}};

    const int arow = tid >> 1;         // 0..127
    const int ak   = (tid & 1) * 8;    // 0 or 8
    const int bk   = tid >> 4;         // 0..15
    const int bn   = (tid & 15) << 2;  // 0..60

    for (int k0 = 0; k0 < D_; k0 += 16) {
        const float4 av0 = *(const float4*)&x[(size_t)(row0 + arow) * D_ + k0 + ak];
        const float4 av1 = *(const float4*)&x[(size_t)(row0 + arow) * D_ + k0 + ak + 4];
        As[ak + 0][arow] = av0.x; As[ak + 1][arow] = av0.y;
        As[ak + 2][arow] = av0.z; As[ak + 3][arow] = av0.w;
        As[ak + 4][arow] = av1.x; As[ak + 5][arow] = av1.y;
        As[ak + 6][arow] = av1.z; As[ak + 7][arow] = av1.w;
        *(float4*)&Bqs[bk][bn] = *(const float4*)&Wq[(size_t)(k0 + bk) * D_ + col0 + bn];
        *(float4*)&Bks[bk][bn] = *(const float4*)&Wk[(size_t)(k0 + bk) * D_ + col0 + bn];
        *(float4*)&Bvs[bk][bn] = *(const float4*)&Wv[(size_t)(k0 + bk) * D_ + col0 + bn];
        __syncthreads();
        #pragma unroll 8
        for (int kk = 0; kk < 16; ++kk) {
            float4 a04 = *(const float4*)&As[kk][ty << 3];
            float4 a14 = *(const float4*)&As[kk][(ty << 3) + 4];
            float4 q4 = *(const float4*)&Bqs[kk][tx << 2];
            float4 k4 = *(const float4*)&Bks[kk][tx << 2];
            float4 v4 = *(const float4*)&Bvs[kk][tx << 2];
            float a[8]  = {a04.x, a04.y, a04.z, a04.w, a14.x, a14.y, a14.z, a14.w};
            float bq[4] = {q4.x, q4.y, q4.z, q4.w};
            float bb[4] = {k4.x, k4.y, k4.z, k4.w};
            float bv[4] = {v4.x, v4.y, v4.z, v4.w};
            #pragma unroll
            for (int i = 0; i < 8; ++i)
                #pragma unroll
                for (int j = 0; j < 4; ++j) {
                    accq[i][j] += a[i] * bq[j];
                    acck[i][j] += a[i] * bb[j];
                    accv[i][j] += a[i] * bv[j];
                }
        }
        __syncthreads();
    }

    #pragma unroll
    for (int i = 0; i < 8; ++i) {
        size_t row = (size_t)row0 + (ty << 3) + i;
        size_t off = row * D_ + col0 + (tx << 2);
        float4 qo, eo, vo;
        qo.x = accq[i][0]; qo.y = accq[i][1]; qo.z = accq[i][2]; qo.w = accq[i][3];
        float e0 = expf(acck[i][0]), e1 = expf(acck[i][1]);
        float e2 = expf(acck[i][2]), e3 = expf(acck[i][3]);
        eo.x = e0; eo.y = e1; eo.z = e2; eo.w = e3;
        vo.x = e0 * accv[i][0]; vo.y = e1 * accv[i][1];
        vo.z = e2 * accv[i][2]; vo.w = e3 * accv[i][3];
        *(float4*)&q[off]   = qo;
        *(float4*)&ek[off]  = eo;
        *(float4*)&ekv[off] = vo;
    }
}

// ---------------------------------------------------------------------------
// K2: global sums over t:  Sk[b,d] = sum_t ek[b,t,d],  Sv likewise.
// ---------------------------------------------------------------------------
__global__ __launch_bounds__(256) void aft_sums(
    const float* __restrict__ ek, const float* __restrict__ ekv,
    float* __restrict__ Sk, float* __restrict__ Sv)
{
    const int idx = blockIdx.x * 256 + threadIdx.x;  // 0..B*D-1
    const int b = idx >> 8;
    const int d = idx & (D_ - 1);
    const int t0 = blockIdx.y * (T_ / 16);
    float sk = 0.f, sv = 0.f;
    size_t base = ((size_t)b * T_ + t0) * D_ + d;
    for (int t = 0; t < T_ / 16; ++t) {
        sk += ek[base + (size_t)t * D_];
        sv += ekv[base + (size_t)t * D_];
    }
    atomicAdd(&Sk[idx], sk);
    atomicAdd(&Sv[idx], sv);
}

// ---------------------------------------------------------------------------
// K3: band coefficients EW[t][j] = exp(w_bias[t, t-127+j]) - 1, j in [0,255).
// ---------------------------------------------------------------------------
__global__ __launch_bounds__(256) void aft_ew(
    const float* __restrict__ wb, float* __restrict__ EW)
{
    const int t = blockIdx.x;
    const int j = threadIdx.x;
    const int s = t - (W_ - 1) + j;
    float v = 0.f;
    if (j < 2 * W_ - 1 && s >= 0 && s < T_)
        v = expf(wb[(size_t)t * T_ + s]) - 1.0f;
    EW[(size_t)t * 256 + j] = v;
}

// ---------------------------------------------------------------------------
// K4: banded num/den + fused epilogue y = sigmoid(q) * (Sv+num)/(Sk+den).
// Block = 64 t x 256 d of one batch; thread = 8 t x 8 d (two float4 halves).
// s staged through LDS in chunks of 16; band coefs staged transposed [s][t].
// ---------------------------------------------------------------------------
__global__ __launch_bounds__(256) void aft_band(
    const float* __restrict__ ek, const float* __restrict__ ekv,
    const float* __restrict__ EW,
    const float* __restrict__ Sk, const float* __restrict__ Sv,
    const float* __restrict__ q, float* __restrict__ y)
{
    __shared__ float eks[16][264];
    __shared__ float ekvs[16][264];
    __shared__ float ews[16][68];   // [s_local][t_local]

    const int tid = threadIdx.x;
    const int b   = blockIdx.y;
    const int t0  = blockIdx.x * 64;
    const int tx  = tid & 31;   // d-quad: d = tx*4 and 128 + tx*4
    const int tg  = tid >> 5;   // t-octet: t = t0 + tg*8 + u

    float4 accn0[8], accn1[8], accd0[8], accd1[8];
    #pragma unroll
    for (int u = 0; u < 8; ++u) {
        accn0[u] = make_float4(0.f, 0.f, 0.f, 0.f);
        accn1[u] = accn0[u]; accd0[u] = accn0[u]; accd1[u] = accn0[u];
    }

    const int s_start = t0 - (W_ - 1);
    const int srow = tid >> 4;          // 0..15
    const int sd   = (tid & 15) * 16;   // 0..240

    for (int c = 0; c < 20; ++c) {
        const int s_base = s_start + c * 16;
        // stage ek/ekv chunk: 16 s x 256 d (64 B per thread per array)
        {
            int s = s_base + srow;
            if (s >= 0 && s < T_) {
                const float4* pk = (const float4*)&ek [(((size_t)b * T_ + s) * D_ + sd)];
                const float4* pv = (const float4*)&ekv[(((size_t)b * T_ + s) * D_ + sd)];
                #pragma unroll
                for (int r = 0; r < 4; ++r) {
                    *(float4*)&eks [srow][sd + r * 4] = pk[r];
                    *(float4*)&ekvs[srow][sd + r * 4] = pv[r];
                }
            } else {
                float4 z = make_float4(0.f, 0.f, 0.f, 0.f);
                #pragma unroll
                for (int r = 0; r < 4; ++r) {
                    *(float4*)&eks [srow][sd + r * 4] = z;
                    *(float4*)&ekvs[srow][sd + r * 4] = z;
                }
            }
        }
        // stage band coefs transposed: 16 s x 64 t
        #pragma unroll
        for (int r = 0; r < 4; ++r) {
            int e  = r * 256 + tid;
            int sl = e >> 6;            // 0..15
            int tl = e & 63;            // 0..63
            int s2 = s_base + sl;
            int j  = s2 - (t0 + tl) + (W_ - 1);
            float wv = 0.f;
            if (j >= 0 && j < 2 * W_ - 1 && s2 >= 0 && s2 < T_)
                wv = EW[(size_t)(t0 + tl) * 256 + j];
            ews[sl][tl] = wv;
        }
        __syncthreads();
        #pragma unroll 4
        for (int sl = 0; sl < 16; ++sl) {
            float4 ke0 = *(const float4*)&eks [sl][tx << 2];
            float4 ke1 = *(const float4*)&eks [sl][128 + (tx << 2)];
            float4 kv0 = *(const float4*)&ekvs[sl][tx << 2];
            float4 kv1 = *(const float4*)&ekvs[sl][128 + (tx << 2)];
            float4 w04 = *(const float4*)&ews[sl][tg << 3];
            float4 w14 = *(const float4*)&ews[sl][(tg << 3) + 4];
            float wv[8] = {w04.x, w04.y, w04.z, w04.w, w14.x, w14.y, w14.z, w14.w};
            #pragma unroll
            for (int u = 0; u < 8; ++u) {
                float w = wv[u];
                accn0[u].x += w * kv0.x; accn0[u].y += w * kv0.y;
                accn0[u].z += w * kv0.z; accn0[u].w += w * kv0.w;
                accn1[u].x += w * kv1.x; accn1[u].y += w * kv1.y;
                accn1[u].z += w * kv1.z; accn1[u].w += w * kv1.w;
                accd0[u].x += w * ke0.x; accd0[u].y += w * ke0.y;
                accd0[u].z += w * ke0.z; accd0[u].w += w * ke0.w;
                accd1[u].x += w * ke1.x; accd1[u].y += w * ke1.y;
                accd1[u].z += w * ke1.z; accd1[u].w += w * ke1.w;
            }
        }
        __syncthreads();
    }

    const int d  = tx << 2;
    const float4 sk0 = *(const float4*)&Sk[b * D_ + d];
    const float4 sk1 = *(const float4*)&Sk[b * D_ + 128 + d];
    const float4 sv0 = *(const float4*)&Sv[b * D_ + d];
    const float4 sv1 = *(const float4*)&Sv[b * D_ + 128 + d];
    #pragma unroll
    for (int u = 0; u < 8; ++u) {
        int t = t0 + (tg << 3) + u;
        size_t off = ((size_t)b * T_ + t) * D_ + d;
        float4 q0 = *(const float4*)&q[off];
        float4 q1 = *(const float4*)&q[off + 128];
        float4 o0, o1;
        o0.x = (1.f / (1.f + expf(-q0.x))) * (sv0.x + accn0[u].x) / (sk0.x + accd0[u].x);
        o0.y = (1.f / (1.f + expf(-q0.y))) * (sv0.y + accn0[u].y) / (sk0.y + accd0[u].y);
        o0.z = (1.f / (1.f + expf(-q0.z))) * (sv0.z + accn0[u].z) / (sk0.z + accd0[u].z);
        o0.w = (1.f / (1.f + expf(-q0.w))) * (sv0.w + accn0[u].w) / (sk0.w + accd0[u].w);
        o1.x = (1.f / (1.f + expf(-q1.x))) * (sv1.x + accn1[u].x) / (sk1.x + accd1[u].x);
        o1.y = (1.f / (1.f + expf(-q1.y))) * (sv1.y + accn1[u].y) / (sk1.y + accd1[u].y);
        o1.z = (1.f / (1.f + expf(-q1.z))) * (sv1.z + accn1[u].z) / (sk1.z + accd1[u].z);
        o1.w = (1.f / (1.f + expf(-q1.w))) * (sv1.w + accn1[u].w) / (sk1.w + accd1[u].w);
        *(float4*)&y[off]       = o0;
        *(float4*)&y[off + 128] = o1;
    }
}

// ---------------------------------------------------------------------------
// K5: output projection GEMM  out = y @ Wo.  128x128 tile, 8x8 per thread.
// ---------------------------------------------------------------------------
__global__ __launch_bounds__(256) void aft_out_gemm(
    const float* __restrict__ A, const float* __restrict__ Bw,
    float* __restrict__ C)
{
    __shared__ float As[16][132];
    __shared__ float Bs[16][132];

    const int tid  = threadIdx.x;
    const int row0 = blockIdx.x * 128;
    const int col0 = blockIdx.y * 128;
    const int tx = tid & 15;   // col group: cols tx*4 and 64+tx*4
    const int ty = tid >> 4;   // row group: 8 rows

    float acc[8][8] = {{0.f}};

    const int arow = tid >> 1;
    const int ak   = (tid & 1) * 8;
    const int bkr  = tid >> 4;         // 0..15
    const int bnr  = (tid & 15) * 8;   // 0..120

    for (int k0 = 0; k0 < D_; k0 += 16) {
        const float4 av0 = *(const float4*)&A[(size_t)(row0 + arow) * D_ + k0 + ak];
        const float4 av1 = *(const float4*)&A[(size_t)(row0 + arow) * D_ + k0 + ak + 4];
        As[ak + 0][arow] = av0.x; As[ak + 1][arow] = av0.y;
        As[ak + 2][arow] = av0.z; As[ak + 3][arow] = av0.w;
        As[ak + 4][arow] = av1.x; As[ak + 5][arow] = av1.y;
        As[ak + 6][arow] = av1.z; As[ak + 7][arow] = av1.w;
        *(float4*)&Bs[bkr][bnr]     = *(const float4*)&Bw[(size_t)(k0 + bkr) * D_ + col0 + bnr];
        *(float4*)&Bs[bkr][bnr + 4] = *(const float4*)&Bw[(size_t)(k0 + bkr) * D_ + col0 + bnr + 4];
        __syncthreads();
        #pragma unroll 8
        for (int kk = 0; kk < 16; ++kk) {
            float4 a04 = *(const float4*)&As[kk][ty << 3];
            float4 a14 = *(const float4*)&As[kk][(ty << 3) + 4];
            float4 b04 = *(const float4*)&Bs[kk][tx << 2];
            float4 b14 = *(const float4*)&Bs[kk][64 + (tx << 2)];
            float a[8] = {a04.x, a04.y, a04.z, a04.w, a14.x, a14.y, a14.z, a14.w};
            float bb[8] = {b04.x, b04.y, b04.z, b04.w, b14.x, b14.y, b14.z, b14.w};
            #pragma unroll
            for (int i = 0; i < 8; ++i)
                #pragma unroll
                for (int j = 0; j < 8; ++j)
                    acc[i][j] += a[i] * bb[j];
        }
        __syncthreads();
    }

    #pragma unroll
    for (int i = 0; i < 8; ++i) {
        size_t row = (size_t)row0 + (ty << 3) + i;
        size_t off = row * D_ + col0 + (tx << 2);
        float4 o0, o1;
        o0.x = acc[i][0]; o0.y = acc[i][1]; o0.z = acc[i][2]; o0.w = acc[i][3];
        o1.x = acc[i][4]; o1.y = acc[i][5]; o1.z = acc[i][6]; o1.w = acc[i][7];
        *(float4*)&C[off]      = o0;
        *(float4*)&C[off + 64] = o1;
    }
}

extern "C" void kernel_launch(void* const* d_in, const int* in_sizes, int n_in,
                              void* d_out, int out_size, void* d_ws, size_t ws_size,
                              hipStream_t stream)
{
    const float* x  = (const float*)d_in[0];
    const float* Wq = (const float*)d_in[1];
    const float* Wk = (const float*)d_in[2];
    const float* Wv = (const float*)d_in[3];
    const float* Wo = (const float*)d_in[4];
    const float* wb = (const float*)d_in[5];
    // window (d_in[6]) is the constant 128, baked in as W_.

    float* ws = (float*)d_ws;
    const size_t N = (size_t)B_ * T_ * D_;   // 8,388,608
    float* q   = ws;
    float* ek  = ws + N;
    float* ekv = ws + 2 * N;
    float* y   = ws + 3 * N;
    float* EW  = ws + 4 * N;                 // T_ * 256 floats
    float* Sk  = EW + (size_t)T_ * 256;      // B_*D_ floats
    float* Sv  = Sk + B_ * D_;               // B_*D_ floats

    hipMemsetAsync(Sk, 0, 2 * B_ * D_ * sizeof(float), stream);

    aft_qkv_gemm<<<dim3(M_ / 128, D_ / 64), 256, 0, stream>>>(x, Wq, Wk, Wv, q, ek, ekv);
    aft_ew<<<dim3(T_), 256, 0, stream>>>(wb, EW);
    aft_sums<<<dim3((B_ * D_) / 256, 16), 256, 0, stream>>>(ek, ekv, Sk, Sv);
    aft_band<<<dim3(T_ / 64, B_), 256, 0, stream>>>(ek, ekv, EW, Sk, Sv, q, y);
    aft_out_gemm<<<dim3(M_ / 128, D_ / 128), 256, 0, stream>>>(y, Wo, (float*)d_out);
}

// Round 3
// 322.614 us; speedup vs baseline: 1.6054x; 1.4458x over previous
//
#include <hip/hip_runtime.h>
#include <math.h>

#define B_ 16
#define T_ 2048
#define D_ 256
#define W_ 128
#define M_ (B_*T_)   // 32768

typedef __attribute__((ext_vector_type(8))) short bf16x8;
typedef __attribute__((ext_vector_type(4))) float f32x4;

static __device__ __forceinline__ unsigned short f32_bf16_rne(float f) {
    unsigned int u = __float_as_uint(f);
    u += 0x7FFF + ((u >> 16) & 1);
    return (unsigned short)(u >> 16);
}
static __device__ __forceinline__ float bf16_f32(unsigned short h) {
    return __uint_as_float(((unsigned int)h) << 16);
}

// ---------------------------------------------------------------------------
// K0: split + transpose the 4 weight matrices into bf16 hi/lo, layout [mat][n][k].
// ---------------------------------------------------------------------------
__global__ __launch_bounds__(256) void aft_split_wT(
    const float* __restrict__ Wq, const float* __restrict__ Wk,
    const float* __restrict__ Wv, const float* __restrict__ Wo,
    unsigned short* __restrict__ Wth, unsigned short* __restrict__ Wtl)
{
    const float* Ws[4] = {Wq, Wk, Wv, Wo};
    const float* W = Ws[blockIdx.x];
    const int n  = blockIdx.y * 16 + (threadIdx.x >> 4);
    const int k0 = (threadIdx.x & 15) * 16;
    size_t obase = ((size_t)blockIdx.x * 256 + n) * 256 + k0;
    #pragma unroll 4
    for (int j = 0; j < 16; ++j) {
        float v = W[(size_t)(k0 + j) * 256 + n];
        unsigned short h = f32_bf16_rne(v);
        Wth[obase + j] = h;
        Wtl[obase + j] = f32_bf16_rne(v - bf16_f32(h));
    }
}

// ---------------------------------------------------------------------------
// K1: QKV projection via split-bf16 MFMA.  Block tile 128 rows x 64 cols x 3
// matrices; 4 waves (2x2); wave tile 64x32 per matrix (4x2 frags 16x16x32).
// A (x, fp32) is split hi/lo during staging.  Epilogue: q, ek=exp(k), ekv.
// ---------------------------------------------------------------------------
__global__ __launch_bounds__(256) void aft_qkv_mfma(
    const float* __restrict__ x,
    const unsigned short* __restrict__ Wth, const unsigned short* __restrict__ Wtl,
    float* __restrict__ qo, float* __restrict__ ek, float* __restrict__ ekv)
{
    __shared__ unsigned short Ah[128][40], Al[128][40];      // pad 40: 2-way banks
    __shared__ unsigned short Bh[3][64][40], Bl[3][64][40];

    const int tid  = threadIdx.x;
    const int row0 = blockIdx.x * 128;
    const int col0 = blockIdx.y * 64;
    const int lane = tid & 63;
    const int wid  = tid >> 6;
    const int wm   = (wid & 1) * 64;
    const int wn   = (wid >> 1) * 32;
    const int qd   = lane >> 4;    // quad
    const int r    = lane & 15;

    f32x4 acc[3][4][2];
    #pragma unroll
    for (int a = 0; a < 3; ++a)
        #pragma unroll
        for (int i = 0; i < 4; ++i)
            #pragma unroll
            for (int j = 0; j < 2; ++j)
                acc[a][i][j] = (f32x4){0.f, 0.f, 0.f, 0.f};

    const int am  = tid >> 1;          // 0..127
    const int akh = (tid & 1) * 16;    // 0 / 16
    const int bn  = tid >> 2;          // 0..63
    const int bkh = (tid & 3) * 8;     // 0,8,16,24

    for (int k0 = 0; k0 < D_; k0 += 32) {
        // stage A: load fp32, split to bf16 hi/lo
        {
            size_t g = (size_t)(row0 + am) * D_ + k0 + akh;
            #pragma unroll
            for (int c = 0; c < 4; ++c) {
                float4 v = *(const float4*)&x[g + c * 4];
                ushort4 h, l;
                h.x = f32_bf16_rne(v.x); l.x = f32_bf16_rne(v.x - bf16_f32(h.x));
                h.y = f32_bf16_rne(v.y); l.y = f32_bf16_rne(v.y - bf16_f32(h.y));
                h.z = f32_bf16_rne(v.z); l.z = f32_bf16_rne(v.z - bf16_f32(h.z));
                h.w = f32_bf16_rne(v.w); l.w = f32_bf16_rne(v.w - bf16_f32(h.w));
                *(ushort4*)&Ah[am][akh + c * 4] = h;
                *(ushort4*)&Al[am][akh + c * 4] = l;
            }
        }
        // stage B: 3 matrices, pre-split bf16 [n][k]
        #pragma unroll
        for (int mat = 0; mat < 3; ++mat) {
            size_t g = ((size_t)mat * 256 + col0 + bn) * 256 + k0 + bkh;
            *(uint4*)&Bh[mat][bn][bkh] = *(const uint4*)&Wth[g];
            *(uint4*)&Bl[mat][bn][bkh] = *(const uint4*)&Wtl[g];
        }
        __syncthreads();

        bf16x8 ah[4], al[4];
        #pragma unroll
        for (int mf = 0; mf < 4; ++mf) {
            ah[mf] = *(const bf16x8*)&Ah[wm + mf * 16 + r][qd * 8];
            al[mf] = *(const bf16x8*)&Al[wm + mf * 16 + r][qd * 8];
        }
        #pragma unroll
        for (int mat = 0; mat < 3; ++mat) {
            #pragma unroll
            for (int nf = 0; nf < 2; ++nf) {
                bf16x8 bh = *(const bf16x8*)&Bh[mat][wn + nf * 16 + r][qd * 8];
                bf16x8 bl = *(const bf16x8*)&Bl[mat][wn + nf * 16 + r][qd * 8];
                #pragma unroll
                for (int mf = 0; mf < 4; ++mf) {
                    acc[mat][mf][nf] = __builtin_amdgcn_mfma_f32_16x16x32_bf16(ah[mf], bh, acc[mat][mf][nf], 0, 0, 0);
                    acc[mat][mf][nf] = __builtin_amdgcn_mfma_f32_16x16x32_bf16(ah[mf], bl, acc[mat][mf][nf], 0, 0, 0);
                    acc[mat][mf][nf] = __builtin_amdgcn_mfma_f32_16x16x32_bf16(al[mf], bh, acc[mat][mf][nf], 0, 0, 0);
                }
            }
        }
        __syncthreads();
    }

    // epilogue: C layout col=lane&15, row=quad*4+reg
    #pragma unroll
    for (int mf = 0; mf < 4; ++mf) {
        #pragma unroll
        for (int nf = 0; nf < 2; ++nf) {
            #pragma unroll
            for (int reg = 0; reg < 4; ++reg) {
                int mrow = row0 + wm + mf * 16 + qd * 4 + reg;
                int ncol = col0 + wn + nf * 16 + r;
                size_t off = (size_t)mrow * D_ + ncol;
                float e = expf(acc[1][mf][nf][reg]);
                qo[off]  = acc[0][mf][nf][reg];
                ek[off]  = e;
                ekv[off] = e * acc[2][mf][nf][reg];
            }
        }
    }
}

// ---------------------------------------------------------------------------
// K2: global sums over t:  Sk[b,d] = sum_t ek[b,t,d],  Sv likewise.
// ---------------------------------------------------------------------------
__global__ __launch_bounds__(256) void aft_sums(
    const float* __restrict__ ek, const float* __restrict__ ekv,
    float* __restrict__ Sk, float* __restrict__ Sv)
{
    const int idx = blockIdx.x * 256 + threadIdx.x;
    const int b = idx >> 8;
    const int d = idx & (D_ - 1);
    const int t0 = blockIdx.y * (T_ / 16);
    float sk = 0.f, sv = 0.f;
    size_t base = ((size_t)b * T_ + t0) * D_ + d;
    for (int t = 0; t < T_ / 16; ++t) {
        sk += ek[base + (size_t)t * D_];
        sv += ekv[base + (size_t)t * D_];
    }
    atomicAdd(&Sk[idx], sk);
    atomicAdd(&Sv[idx], sv);
}

// ---------------------------------------------------------------------------
// K3: banded num/den + fused epilogue; y emitted as bf16 hi/lo for out-GEMM.
// Band coefs exp(wb)-1 computed inline during staging (no EW array).
// ---------------------------------------------------------------------------
__global__ __launch_bounds__(256) void aft_band(
    const float* __restrict__ ek, const float* __restrict__ ekv,
    const float* __restrict__ wb,
    const float* __restrict__ Sk, const float* __restrict__ Sv,
    const float* __restrict__ q,
    unsigned short* __restrict__ yh, unsigned short* __restrict__ yl)
{
    __shared__ float eks[16][264];
    __shared__ float ekvs[16][264];
    __shared__ float ews[16][68];   // [s_local][t_local]

    const int tid = threadIdx.x;
    const int b   = blockIdx.y;
    const int t0  = blockIdx.x * 64;
    const int tx  = tid & 31;
    const int tg  = tid >> 5;

    float4 accn0[8], accn1[8], accd0[8], accd1[8];
    #pragma unroll
    for (int u = 0; u < 8; ++u) {
        accn0[u] = make_float4(0.f, 0.f, 0.f, 0.f);
        accn1[u] = accn0[u]; accd0[u] = accn0[u]; accd1[u] = accn0[u];
    }

    const int s_start = t0 - (W_ - 1);
    const int srow = tid >> 4;
    const int sd   = (tid & 15) * 16;

    for (int c = 0; c < 20; ++c) {
        const int s_base = s_start + c * 16;
        {
            int s = s_base + srow;
            if (s >= 0 && s < T_) {
                const float4* pk = (const float4*)&ek [(((size_t)b * T_ + s) * D_ + sd)];
                const float4* pv = (const float4*)&ekv[(((size_t)b * T_ + s) * D_ + sd)];
                #pragma unroll
                for (int rr = 0; rr < 4; ++rr) {
                    *(float4*)&eks [srow][sd + rr * 4] = pk[rr];
                    *(float4*)&ekvs[srow][sd + rr * 4] = pv[rr];
                }
            } else {
                float4 z = make_float4(0.f, 0.f, 0.f, 0.f);
                #pragma unroll
                for (int rr = 0; rr < 4; ++rr) {
                    *(float4*)&eks [srow][sd + rr * 4] = z;
                    *(float4*)&ekvs[srow][sd + rr * 4] = z;
                }
            }
        }
        // band coefs from wb directly: 16 s x 64 t (coalesced along s)
        #pragma unroll
        for (int rr = 0; rr < 4; ++rr) {
            int e  = rr * 256 + tid;
            int tl = e >> 4;            // 0..63
            int sl = e & 15;            // 0..15
            int s2 = s_base + sl;
            int tt = t0 + tl;
            int j  = s2 - tt;
            float wv = 0.f;
            if (j > -W_ && j < W_ && s2 >= 0 && s2 < T_)
                wv = expf(wb[(size_t)tt * T_ + s2]) - 1.0f;
            ews[sl][tl] = wv;
        }
        __syncthreads();
        #pragma unroll 4
        for (int sl = 0; sl < 16; ++sl) {
            float4 ke0 = *(const float4*)&eks [sl][tx << 2];
            float4 ke1 = *(const float4*)&eks [sl][128 + (tx << 2)];
            float4 kv0 = *(const float4*)&ekvs[sl][tx << 2];
            float4 kv1 = *(const float4*)&ekvs[sl][128 + (tx << 2)];
            float4 w04 = *(const float4*)&ews[sl][tg << 3];
            float4 w14 = *(const float4*)&ews[sl][(tg << 3) + 4];
            float wv[8] = {w04.x, w04.y, w04.z, w04.w, w14.x, w14.y, w14.z, w14.w};
            #pragma unroll
            for (int u = 0; u < 8; ++u) {
                float w = wv[u];
                accn0[u].x += w * kv0.x; accn0[u].y += w * kv0.y;
                accn0[u].z += w * kv0.z; accn0[u].w += w * kv0.w;
                accn1[u].x += w * kv1.x; accn1[u].y += w * kv1.y;
                accn1[u].z += w * kv1.z; accn1[u].w += w * kv1.w;
                accd0[u].x += w * ke0.x; accd0[u].y += w * ke0.y;
                accd0[u].z += w * ke0.z; accd0[u].w += w * ke0.w;
                accd1[u].x += w * ke1.x; accd1[u].y += w * ke1.y;
                accd1[u].z += w * ke1.z; accd1[u].w += w * ke1.w;
            }
        }
        __syncthreads();
    }

    const int d  = tx << 2;
    const float4 sk0 = *(const float4*)&Sk[b * D_ + d];
    const float4 sk1 = *(const float4*)&Sk[b * D_ + 128 + d];
    const float4 sv0 = *(const float4*)&Sv[b * D_ + d];
    const float4 sv1 = *(const float4*)&Sv[b * D_ + 128 + d];
    #pragma unroll
    for (int u = 0; u < 8; ++u) {
        int t = t0 + (tg << 3) + u;
        size_t off = ((size_t)b * T_ + t) * D_ + d;
        float4 q0 = *(const float4*)&q[off];
        float4 q1 = *(const float4*)&q[off + 128];
        float o[8];
        o[0] = (1.f / (1.f + expf(-q0.x))) * (sv0.x + accn0[u].x) / (sk0.x + accd0[u].x);
        o[1] = (1.f / (1.f + expf(-q0.y))) * (sv0.y + accn0[u].y) / (sk0.y + accd0[u].y);
        o[2] = (1.f / (1.f + expf(-q0.z))) * (sv0.z + accn0[u].z) / (sk0.z + accd0[u].z);
        o[3] = (1.f / (1.f + expf(-q0.w))) * (sv0.w + accn0[u].w) / (sk0.w + accd0[u].w);
        o[4] = (1.f / (1.f + expf(-q1.x))) * (sv1.x + accn1[u].x) / (sk1.x + accd1[u].x);
        o[5] = (1.f / (1.f + expf(-q1.y))) * (sv1.y + accn1[u].y) / (sk1.y + accd1[u].y);
        o[6] = (1.f / (1.f + expf(-q1.z))) * (sv1.z + accn1[u].z) / (sk1.z + accd1[u].z);
        o[7] = (1.f / (1.f + expf(-q1.w))) * (sv1.w + accn1[u].w) / (sk1.w + accd1[u].w);
        ushort4 h0, l0, h1, l1;
        h0.x = f32_bf16_rne(o[0]); l0.x = f32_bf16_rne(o[0] - bf16_f32(h0.x));
        h0.y = f32_bf16_rne(o[1]); l0.y = f32_bf16_rne(o[1] - bf16_f32(h0.y));
        h0.z = f32_bf16_rne(o[2]); l0.z = f32_bf16_rne(o[2] - bf16_f32(h0.z));
        h0.w = f32_bf16_rne(o[3]); l0.w = f32_bf16_rne(o[3] - bf16_f32(h0.w));
        h1.x = f32_bf16_rne(o[4]); l1.x = f32_bf16_rne(o[4] - bf16_f32(h1.x));
        h1.y = f32_bf16_rne(o[5]); l1.y = f32_bf16_rne(o[5] - bf16_f32(h1.y));
        h1.z = f32_bf16_rne(o[6]); l1.z = f32_bf16_rne(o[6] - bf16_f32(h1.z));
        h1.w = f32_bf16_rne(o[7]); l1.w = f32_bf16_rne(o[7] - bf16_f32(h1.w));
        *(ushort4*)&yh[off]       = h0;
        *(ushort4*)&yl[off]       = l0;
        *(ushort4*)&yh[off + 128] = h1;
        *(ushort4*)&yl[off + 128] = l1;
    }
}

// ---------------------------------------------------------------------------
// K4: output projection via split-bf16 MFMA.  128x128 tile, wave tile 64x64.
// ---------------------------------------------------------------------------
__global__ __launch_bounds__(256) void aft_out_mfma(
    const unsigned short* __restrict__ yh, const unsigned short* __restrict__ yl,
    const unsigned short* __restrict__ Woth, const unsigned short* __restrict__ Wotl,
    float* __restrict__ out)
{
    __shared__ unsigned short Ah[128][40], Al[128][40];
    __shared__ unsigned short Bh[128][40], Bl[128][40];

    const int tid  = threadIdx.x;
    const int row0 = blockIdx.x * 128;
    const int col0 = blockIdx.y * 128;
    const int lane = tid & 63;
    const int wid  = tid >> 6;
    const int wm   = (wid & 1) * 64;
    const int wn   = (wid >> 1) * 64;
    const int qd   = lane >> 4;
    const int r    = lane & 15;

    f32x4 acc[4][4];
    #pragma unroll
    for (int i = 0; i < 4; ++i)
        #pragma unroll
        for (int j = 0; j < 4; ++j)
            acc[i][j] = (f32x4){0.f, 0.f, 0.f, 0.f};

    const int am  = tid >> 1;
    const int akh = (tid & 1) * 16;

    for (int k0 = 0; k0 < D_; k0 += 32) {
        {
            size_t g = (size_t)(row0 + am) * D_ + k0 + akh;
            *(uint4*)&Ah[am][akh]     = *(const uint4*)&yh[g];
            *(uint4*)&Ah[am][akh + 8] = *(const uint4*)&yh[g + 8];
            *(uint4*)&Al[am][akh]     = *(const uint4*)&yl[g];
            *(uint4*)&Al[am][akh + 8] = *(const uint4*)&yl[g + 8];
        }
        {
            size_t g = (size_t)(col0 + am) * 256 + k0 + akh;
            *(uint4*)&Bh[am][akh]     = *(const uint4*)&Woth[g];
            *(uint4*)&Bh[am][akh + 8] = *(const uint4*)&Woth[g + 8];
            *(uint4*)&Bl[am][akh]     = *(const uint4*)&Wotl[g];
            *(uint4*)&Bl[am][akh + 8] = *(const uint4*)&Wotl[g + 8];
        }
        __syncthreads();

        bf16x8 ah[4], al[4];
        #pragma unroll
        for (int mf = 0; mf < 4; ++mf) {
            ah[mf] = *(const bf16x8*)&Ah[wm + mf * 16 + r][qd * 8];
            al[mf] = *(const bf16x8*)&Al[wm + mf * 16 + r][qd * 8];
        }
        #pragma unroll
        for (int nf = 0; nf < 4; ++nf) {
            bf16x8 bh = *(const bf16x8*)&Bh[wn + nf * 16 + r][qd * 8];
            bf16x8 bl = *(const bf16x8*)&Bl[wn + nf * 16 + r][qd * 8];
            #pragma unroll
            for (int mf = 0; mf < 4; ++mf) {
                acc[mf][nf] = __builtin_amdgcn_mfma_f32_16x16x32_bf16(ah[mf], bh, acc[mf][nf], 0, 0, 0);
                acc[mf][nf] = __builtin_amdgcn_mfma_f32_16x16x32_bf16(ah[mf], bl, acc[mf][nf], 0, 0, 0);
                acc[mf][nf] = __builtin_amdgcn_mfma_f32_16x16x32_bf16(al[mf], bh, acc[mf][nf], 0, 0, 0);
            }
        }
        __syncthreads();
    }

    #pragma unroll
    for (int mf = 0; mf < 4; ++mf) {
        #pragma unroll
        for (int nf = 0; nf < 4; ++nf) {
            #pragma unroll
            for (int reg = 0; reg < 4; ++reg) {
                int mrow = row0 + wm + mf * 16 + qd * 4 + reg;
                int ncol = col0 + wn + nf * 16 + r;
                out[(size_t)mrow * D_ + ncol] = acc[mf][nf][reg];
            }
        }
    }
}

extern "C" void kernel_launch(void* const* d_in, const int* in_sizes, int n_in,
                              void* d_out, int out_size, void* d_ws, size_t ws_size,
                              hipStream_t stream)
{
    const float* x  = (const float*)d_in[0];
    const float* Wq = (const float*)d_in[1];
    const float* Wk = (const float*)d_in[2];
    const float* Wv = (const float*)d_in[3];
    const float* Wo = (const float*)d_in[4];
    const float* wb = (const float*)d_in[5];
    // window (d_in[6]) is the constant 128, baked in as W_.

    float* ws = (float*)d_ws;
    const size_t N = (size_t)B_ * T_ * D_;   // 8,388,608
    float* q   = ws;
    float* ek  = ws + N;
    float* ekv = ws + 2 * N;
    float* Sk  = ws + 3 * N;
    float* Sv  = Sk + B_ * D_;
    unsigned short* Wth = (unsigned short*)(Sv + B_ * D_);  // 4*256*256
    unsigned short* Wtl = Wth + 4 * 256 * 256;
    unsigned short* yh  = Wtl + 4 * 256 * 256;              // N ushort
    unsigned short* yl  = yh + N;

    hipMemsetAsync(Sk, 0, 2 * B_ * D_ * sizeof(float), stream);

    aft_split_wT<<<dim3(4, 16), 256, 0, stream>>>(Wq, Wk, Wv, Wo, Wth, Wtl);
    aft_qkv_mfma<<<dim3(M_ / 128, D_ / 64), 256, 0, stream>>>(x, Wth, Wtl, q, ek, ekv);
    aft_sums<<<dim3((B_ * D_) / 256, 16), 256, 0, stream>>>(ek, ekv, Sk, Sv);
    aft_band<<<dim3(T_ / 64, B_), 256, 0, stream>>>(ek, ekv, wb, Sk, Sv, q, yh, yl);
    aft_out_mfma<<<dim3(M_ / 128, D_ / 128), 256, 0, stream>>>(yh, yl, Wth + 3 * 65536, Wtl + 3 * 65536, (float*)d_out);
}

// Round 4
// 213.790 us; speedup vs baseline: 2.4226x; 1.5090x over previous
//
#include <hip/hip_runtime.h>
#include <math.h>

#define B_ 16
#define T_ 2048
#define D_ 256
#define W_ 128
#define M_ (B_*T_)   // 32768

typedef __attribute__((ext_vector_type(8))) short bf16x8;
typedef __attribute__((ext_vector_type(4))) float f32x4;
typedef unsigned short u16;

static __device__ __forceinline__ u16 f32_bf16_rne(float f) {
    unsigned int u = __float_as_uint(f);
    u += 0x7FFF + ((u >> 16) & 1);
    return (u16)(u >> 16);
}
static __device__ __forceinline__ float bf16_f32(u16 h) {
    return __uint_as_float(((unsigned int)h) << 16);
}

// ---------------------------------------------------------------------------
// K0: split + transpose the 4 weight matrices into bf16 hi/lo, layout [mat][n][k].
// ---------------------------------------------------------------------------
__global__ __launch_bounds__(256) void aft_split_wT(
    const float* __restrict__ Wq, const float* __restrict__ Wk,
    const float* __restrict__ Wv, const float* __restrict__ Wo,
    u16* __restrict__ Wth, u16* __restrict__ Wtl)
{
    const float* Ws[4] = {Wq, Wk, Wv, Wo};
    const float* W = Ws[blockIdx.x];
    const int n  = blockIdx.y * 16 + (threadIdx.x >> 4);
    const int k0 = (threadIdx.x & 15) * 16;
    size_t obase = ((size_t)blockIdx.x * 256 + n) * 256 + k0;
    #pragma unroll 4
    for (int j = 0; j < 16; ++j) {
        float v = W[(size_t)(k0 + j) * 256 + n];
        u16 h = f32_bf16_rne(v);
        Wth[obase + j] = h;
        Wtl[obase + j] = f32_bf16_rne(v - bf16_f32(h));
    }
}

// ---------------------------------------------------------------------------
// K0b: banded EW precompute.  EWb[t][j] (j in [0,320)) = exp(wb[t][s])-1 for
// s = (t & ~63) - 128 + j inside the band, else 0.  bf16, 16B-aligned rows.
// ---------------------------------------------------------------------------
__global__ void aft_ewb(const float* __restrict__ wb, u16* __restrict__ EWb)
{
    const int t = blockIdx.x;
    const int j = threadIdx.x;   // blockDim = 320
    const int s = (t & ~63) - 128 + j;
    const int dlt = s - t;
    float v = 0.f;
    if (s >= 0 && s < T_ && dlt > -W_ && dlt < W_)
        v = expf(wb[(size_t)t * T_ + s]) - 1.0f;
    EWb[(size_t)t * 320 + j] = f32_bf16_rne(v);
}

// ---------------------------------------------------------------------------
// K1: QKV projection via split-bf16 MFMA (128x64x3 tile).  Epilogue
// LDS-transposes outputs: ekT[b][n][s] (n<256: exp(k), n>=256: exp(k)*v),
// sigqT[b][d][t] = sigmoid(q), all bf16.
// ---------------------------------------------------------------------------
__global__ __launch_bounds__(256) void aft_qkv_mfma(
    const float* __restrict__ x,
    const u16* __restrict__ Wth, const u16* __restrict__ Wtl,
    u16* __restrict__ ekT, u16* __restrict__ sigqT)
{
    __shared__ alignas(16) u16 sm[25600];
    u16* Ah = sm;              // [128][40]
    u16* Al = sm + 5120;
    u16* Bh = sm + 10240;      // [3][64][40]
    u16* Bl = sm + 17920;
    u16* Tr = sm;              // [64][136] epilogue reuse

    const int tid  = threadIdx.x;
    const int row0 = blockIdx.x * 128;
    const int col0 = blockIdx.y * 64;
    const int b    = row0 >> 11;
    const int t0g  = row0 & (T_ - 1);
    const int lane = tid & 63;
    const int wid  = tid >> 6;
    const int wm   = (wid & 1) * 64;
    const int wn   = (wid >> 1) * 32;
    const int qd   = lane >> 4;
    const int r    = lane & 15;

    f32x4 acc[3][4][2];
    #pragma unroll
    for (int a = 0; a < 3; ++a)
        #pragma unroll
        for (int i = 0; i < 4; ++i)
            #pragma unroll
            for (int j = 0; j < 2; ++j)
                acc[a][i][j] = (f32x4){0.f, 0.f, 0.f, 0.f};

    const int am  = tid >> 1;
    const int akh = (tid & 1) * 16;
    const int bn  = tid >> 2;
    const int bkh = (tid & 3) * 8;

    for (int k0 = 0; k0 < D_; k0 += 32) {
        {
            size_t g = (size_t)(row0 + am) * D_ + k0 + akh;
            #pragma unroll
            for (int c = 0; c < 4; ++c) {
                float4 v = *(const float4*)&x[g + c * 4];
                ushort4 h, l;
                h.x = f32_bf16_rne(v.x); l.x = f32_bf16_rne(v.x - bf16_f32(h.x));
                h.y = f32_bf16_rne(v.y); l.y = f32_bf16_rne(v.y - bf16_f32(h.y));
                h.z = f32_bf16_rne(v.z); l.z = f32_bf16_rne(v.z - bf16_f32(h.z));
                h.w = f32_bf16_rne(v.w); l.w = f32_bf16_rne(v.w - bf16_f32(h.w));
                *(ushort4*)&Ah[am * 40 + akh + c * 4] = h;
                *(ushort4*)&Al[am * 40 + akh + c * 4] = l;
            }
        }
        #pragma unroll
        for (int mat = 0; mat < 3; ++mat) {
            size_t g = ((size_t)mat * 256 + col0 + bn) * 256 + k0 + bkh;
            *(uint4*)&Bh[mat * 2560 + bn * 40 + bkh] = *(const uint4*)&Wth[g];
            *(uint4*)&Bl[mat * 2560 + bn * 40 + bkh] = *(const uint4*)&Wtl[g];
        }
        __syncthreads();

        bf16x8 ah[4], al[4];
        #pragma unroll
        for (int mf = 0; mf < 4; ++mf) {
            ah[mf] = *(const bf16x8*)&Ah[(wm + mf * 16 + r) * 40 + qd * 8];
            al[mf] = *(const bf16x8*)&Al[(wm + mf * 16 + r) * 40 + qd * 8];
        }
        #pragma unroll
        for (int mat = 0; mat < 3; ++mat) {
            #pragma unroll
            for (int nf = 0; nf < 2; ++nf) {
                bf16x8 bh = *(const bf16x8*)&Bh[mat * 2560 + (wn + nf * 16 + r) * 40 + qd * 8];
                bf16x8 bl = *(const bf16x8*)&Bl[mat * 2560 + (wn + nf * 16 + r) * 40 + qd * 8];
                #pragma unroll
                for (int mf = 0; mf < 4; ++mf) {
                    acc[mat][mf][nf] = __builtin_amdgcn_mfma_f32_16x16x32_bf16(ah[mf], bh, acc[mat][mf][nf], 0, 0, 0);
                    acc[mat][mf][nf] = __builtin_amdgcn_mfma_f32_16x16x32_bf16(ah[mf], bl, acc[mat][mf][nf], 0, 0, 0);
                    acc[mat][mf][nf] = __builtin_amdgcn_mfma_f32_16x16x32_bf16(al[mf], bh, acc[mat][mf][nf], 0, 0, 0);
                }
            }
        }
        __syncthreads();
    }

    // epilogue: 3 LDS-transpose rounds (ek, ekv, sigq) -> global bf16
    const int dl_r = tid >> 2;            // 0..63
    const int tseg = (tid & 3) * 32;      // 0..96
    #pragma unroll
    for (int round = 0; round < 3; ++round) {
        __syncthreads();
        #pragma unroll
        for (int mf = 0; mf < 4; ++mf) {
            #pragma unroll
            for (int nf = 0; nf < 2; ++nf) {
                ushort4 o;
                float vals[4];
                #pragma unroll
                for (int reg = 0; reg < 4; ++reg) {
                    float qv = acc[0][mf][nf][reg];
                    float kv = acc[1][mf][nf][reg];
                    float vv = acc[2][mf][nf][reg];
                    if (round == 0)      vals[reg] = expf(kv);
                    else if (round == 1) vals[reg] = expf(kv) * vv;
                    else                 vals[reg] = 1.f / (1.f + expf(-qv));
                }
                o.x = f32_bf16_rne(vals[0]); o.y = f32_bf16_rne(vals[1]);
                o.z = f32_bf16_rne(vals[2]); o.w = f32_bf16_rne(vals[3]);
                int dl = wn + nf * 16 + r;
                int tt = wm + mf * 16 + qd * 4;
                *(ushort4*)&Tr[dl * 136 + tt] = o;
            }
        }
        __syncthreads();
        u16* dst;
        if (round == 0)      dst = ekT   + ((size_t)(b * 512 + col0 + dl_r)) * 2048;
        else if (round == 1) dst = ekT   + ((size_t)(b * 512 + 256 + col0 + dl_r)) * 2048;
        else                 dst = sigqT + ((size_t)(b * 256 + col0 + dl_r)) * 2048;
        dst += t0g + tseg;
        const u16* srcp = &Tr[dl_r * 136 + tseg];
        #pragma unroll
        for (int i = 0; i < 4; ++i)
            *(uint4*)&dst[i * 8] = *(const uint4*)&srcp[i * 8];
    }
}

// ---------------------------------------------------------------------------
// K2: row sums of ekT -> Sk (n<256), Sv (n>=256).  One wave per row.
// ---------------------------------------------------------------------------
__global__ __launch_bounds__(256) void aft_sums(
    const u16* __restrict__ ekT, float* __restrict__ Sk, float* __restrict__ Sv)
{
    const int wid  = threadIdx.x >> 6;
    const int lane = threadIdx.x & 63;
    const int row  = blockIdx.x * 4 + wid;   // 0..8191
    const int b = row >> 9, n = row & 511;
    const u16* p = ekT + (size_t)row * 2048 + lane * 32;
    float s = 0.f;
    #pragma unroll
    for (int c = 0; c < 4; ++c) {
        union { uint4 v; u16 h[8]; } u;
        u.v = *(const uint4*)&p[c * 8];
        #pragma unroll
        for (int i = 0; i < 8; ++i) s += bf16_f32(u.h[i]);
    }
    #pragma unroll
    for (int off = 32; off >= 1; off >>= 1) s += __shfl_down(s, off, 64);
    if (lane == 0) {
        if (n < 256) Sk[b * 256 + n] = s;
        else         Sv[b * 256 + n - 256] = s;
    }
}

// ---------------------------------------------------------------------------
// K3: banded num/den via bf16 MFMA.  Block = 64 t x 256 d, one batch.
// Wave = 64t x 64d holding BOTH den (A*ek) and num (A*ekv) accumulators.
// Epilogue: y = sigmoid(q)*(Sv+num)/(Sk+den) -> yT[b][d][t] bf16.
// ---------------------------------------------------------------------------
__global__ __launch_bounds__(256) void aft_band_mfma(
    const u16* __restrict__ EWb, const u16* __restrict__ ekT,
    const u16* __restrict__ sigqT,
    const float* __restrict__ Sk, const float* __restrict__ Sv,
    u16* __restrict__ yT)
{
    __shared__ alignas(16) u16 sm[23040];
    u16* Aw  = sm;          // [64][40]
    u16* Bkv = sm + 2560;   // [512][40] : rows 0..255 ek, 256..511 ekv

    const int tid  = threadIdx.x;
    const int t0   = blockIdx.x * 64;
    const int b    = blockIdx.y;
    const int lane = tid & 63;
    const int wid  = tid >> 6;
    const int wn   = wid * 64;
    const int qd   = lane >> 4;
    const int r    = lane & 15;

    f32x4 accn[4][4], accd[4][4];
    #pragma unroll
    for (int i = 0; i < 4; ++i)
        #pragma unroll
        for (int j = 0; j < 4; ++j) {
            accn[i][j] = (f32x4){0.f, 0.f, 0.f, 0.f};
            accd[i][j] = (f32x4){0.f, 0.f, 0.f, 0.f};
        }

    const int atl = tid >> 2;          // 0..63
    const int ak8 = (tid & 3) * 8;     // 0,8,16,24

    for (int c = 0; c < 10; ++c) {
        const int sc = t0 - 128 + c * 32;
        if (sc < 0 || sc >= T_) continue;   // uniform per block; EW there is 0
        __syncthreads();
        *(uint4*)&Aw[atl * 40 + ak8] =
            *(const uint4*)&EWb[(size_t)(t0 + atl) * 320 + c * 32 + ak8];
        #pragma unroll
        for (int rr = 0; rr < 8; ++rr) {
            int n = rr * 64 + atl;
            *(uint4*)&Bkv[n * 40 + ak8] =
                *(const uint4*)&ekT[((size_t)(b * 512) + n) * 2048 + sc + ak8];
        }
        __syncthreads();

        bf16x8 af[4];
        #pragma unroll
        for (int mf = 0; mf < 4; ++mf)
            af[mf] = *(const bf16x8*)&Aw[(mf * 16 + r) * 40 + qd * 8];
        #pragma unroll
        for (int nf = 0; nf < 4; ++nf) {
            bf16x8 be = *(const bf16x8*)&Bkv[(wn + nf * 16 + r) * 40 + qd * 8];
            bf16x8 bv = *(const bf16x8*)&Bkv[(256 + wn + nf * 16 + r) * 40 + qd * 8];
            #pragma unroll
            for (int mf = 0; mf < 4; ++mf) {
                accd[mf][nf] = __builtin_amdgcn_mfma_f32_16x16x32_bf16(af[mf], be, accd[mf][nf], 0, 0, 0);
                accn[mf][nf] = __builtin_amdgcn_mfma_f32_16x16x32_bf16(af[mf], bv, accn[mf][nf], 0, 0, 0);
            }
        }
    }

    #pragma unroll
    for (int nf = 0; nf < 4; ++nf) {
        const int d = wn + nf * 16 + r;
        const float skq = Sk[(b << 8) + d];
        const float svq = Sv[(b << 8) + d];
        #pragma unroll
        for (int mf = 0; mf < 4; ++mf) {
            const int tt = t0 + mf * 16 + qd * 4;
            size_t off = ((size_t)(b << 8) + d) * 2048 + tt;
            ushort4 sg = *(const ushort4*)&sigqT[off];
            ushort4 yo;
            float y0 = bf16_f32(sg.x) * (svq + accn[mf][nf][0]) / (skq + accd[mf][nf][0]);
            float y1 = bf16_f32(sg.y) * (svq + accn[mf][nf][1]) / (skq + accd[mf][nf][1]);
            float y2 = bf16_f32(sg.z) * (svq + accn[mf][nf][2]) / (skq + accd[mf][nf][2]);
            float y3 = bf16_f32(sg.w) * (svq + accn[mf][nf][3]) / (skq + accd[mf][nf][3]);
            yo.x = f32_bf16_rne(y0); yo.y = f32_bf16_rne(y1);
            yo.z = f32_bf16_rne(y2); yo.w = f32_bf16_rne(y3);
            *(ushort4*)&yT[off] = yo;
        }
    }
}

// ---------------------------------------------------------------------------
// K4: out = y @ Wo via bf16 MFMA (y single bf16, Wo split hi/lo).  A staged
// from yT[b][d][t] with LDS transpose.  128x128 tile.
// ---------------------------------------------------------------------------
__global__ __launch_bounds__(256) void aft_out_mfma(
    const u16* __restrict__ yT,
    const u16* __restrict__ Woth, const u16* __restrict__ Wotl,
    float* __restrict__ out)
{
    __shared__ alignas(16) u16 sm[15360];
    u16* As = sm;           // [128][40]
    u16* Bh = sm + 5120;    // [128][40]
    u16* Bl = sm + 10240;

    const int tid  = threadIdx.x;
    const int row0 = blockIdx.x * 128;
    const int col0 = blockIdx.y * 128;
    const int b    = row0 >> 11;
    const int t0g  = row0 & (T_ - 1);
    const int lane = tid & 63;
    const int wid  = tid >> 6;
    const int wm   = (wid & 1) * 64;
    const int wn   = (wid >> 1) * 64;
    const int qd   = lane >> 4;
    const int r    = lane & 15;

    f32x4 acc[4][4];
    #pragma unroll
    for (int i = 0; i < 4; ++i)
        #pragma unroll
        for (int j = 0; j < 4; ++j)
            acc[i][j] = (f32x4){0.f, 0.f, 0.f, 0.f};

    const int dloc = tid & 31;
    const int tb   = (tid >> 5) * 16;
    const int bn   = tid >> 1;
    const int bkh  = (tid & 1) * 16;

    for (int k0 = 0; k0 < D_; k0 += 32) {
        {
            const u16* src = yT + ((size_t)(b * 256) + k0 + dloc) * 2048 + t0g + tb;
            union { uint4 v[2]; u16 h[16]; } u;
            u.v[0] = *(const uint4*)&src[0];
            u.v[1] = *(const uint4*)&src[8];
            #pragma unroll
            for (int i = 0; i < 16; ++i)
                As[(tb + i) * 40 + dloc] = u.h[i];
        }
        {
            size_t g = (size_t)(col0 + bn) * 256 + k0 + bkh;
            *(uint4*)&Bh[bn * 40 + bkh]     = *(const uint4*)&Woth[g];
            *(uint4*)&Bh[bn * 40 + bkh + 8] = *(const uint4*)&Woth[g + 8];
            *(uint4*)&Bl[bn * 40 + bkh]     = *(const uint4*)&Wotl[g];
            *(uint4*)&Bl[bn * 40 + bkh + 8] = *(const uint4*)&Wotl[g + 8];
        }
        __syncthreads();

        bf16x8 af[4];
        #pragma unroll
        for (int mf = 0; mf < 4; ++mf)
            af[mf] = *(const bf16x8*)&As[(wm + mf * 16 + r) * 40 + qd * 8];
        #pragma unroll
        for (int nf = 0; nf < 4; ++nf) {
            bf16x8 bh = *(const bf16x8*)&Bh[(wn + nf * 16 + r) * 40 + qd * 8];
            bf16x8 bl = *(const bf16x8*)&Bl[(wn + nf * 16 + r) * 40 + qd * 8];
            #pragma unroll
            for (int mf = 0; mf < 4; ++mf) {
                acc[mf][nf] = __builtin_amdgcn_mfma_f32_16x16x32_bf16(af[mf], bh, acc[mf][nf], 0, 0, 0);
                acc[mf][nf] = __builtin_amdgcn_mfma_f32_16x16x32_bf16(af[mf], bl, acc[mf][nf], 0, 0, 0);
            }
        }
        __syncthreads();
    }

    #pragma unroll
    for (int mf = 0; mf < 4; ++mf)
        #pragma unroll
        for (int nf = 0; nf < 4; ++nf)
            #pragma unroll
            for (int reg = 0; reg < 4; ++reg) {
                int mrow = row0 + wm + mf * 16 + qd * 4 + reg;
                int ncol = col0 + wn + nf * 16 + r;
                out[(size_t)mrow * D_ + ncol] = acc[mf][nf][reg];
            }
}

extern "C" void kernel_launch(void* const* d_in, const int* in_sizes, int n_in,
                              void* d_out, int out_size, void* d_ws, size_t ws_size,
                              hipStream_t stream)
{
    const float* x  = (const float*)d_in[0];
    const float* Wq = (const float*)d_in[1];
    const float* Wk = (const float*)d_in[2];
    const float* Wv = (const float*)d_in[3];
    const float* Wo = (const float*)d_in[4];
    const float* wb = (const float*)d_in[5];
    // window (d_in[6]) is the constant 128, baked in as W_.

    u16* Wth   = (u16*)d_ws;                 // 4*65536
    u16* Wtl   = Wth + 262144;
    u16* EWb   = Wtl + 262144;               // 2048*320
    u16* ekT   = EWb + 655360;               // 16*512*2048
    u16* sigqT = ekT + 16777216;             // 16*256*2048
    u16* yT    = sigqT + 8388608;            // 16*256*2048
    float* Sk  = (float*)(yT + 8388608);     // 4096
    float* Sv  = Sk + 4096;                  // 4096

    aft_split_wT<<<dim3(4, 16), 256, 0, stream>>>(Wq, Wk, Wv, Wo, Wth, Wtl);
    aft_ewb<<<dim3(T_), 320, 0, stream>>>(wb, EWb);
    aft_qkv_mfma<<<dim3(M_ / 128, 4), 256, 0, stream>>>(x, Wth, Wtl, ekT, sigqT);
    aft_sums<<<dim3(8192 / 4), 256, 0, stream>>>(ekT, Sk, Sv);
    aft_band_mfma<<<dim3(T_ / 64, B_), 256, 0, stream>>>(EWb, ekT, sigqT, Sk, Sv, yT);
    aft_out_mfma<<<dim3(M_ / 128, 2), 256, 0, stream>>>(yT, Wth + 3 * 65536, Wtl + 3 * 65536, (float*)d_out);
}